// Round 11
// baseline (392.807 us; speedup 1.0000x reference)
//
#include <hip/hip_runtime.h>
#include <hip/hip_bf16.h>

typedef __hip_bfloat16 bf16;
typedef short bf16x8 __attribute__((ext_vector_type(8)));
typedef float f32x4  __attribute__((ext_vector_type(4)));

static constexpr int D_IN  = 128;
static constexpr int D_H   = 256;
static constexpr int D_CAT = 768;

__device__ __forceinline__ float lrelu(float v){ return v > 0.f ? v : 0.2f*v; }
__device__ __forceinline__ bf16  f2b(float v){ return __float2bfloat16(v); }
__device__ __forceinline__ unsigned packb(float lo, float hi){
  bf16 a = f2b(lo), b = f2b(hi);
  unsigned short ua, ub;
  __builtin_memcpy(&ua, &a, 2); __builtin_memcpy(&ub, &b, 2);
  return (unsigned)ua | ((unsigned)ub << 16);
}
__device__ __forceinline__ short bbits(float v){
  bf16 h = f2b(v); short s; __builtin_memcpy(&s, &h, 2); return s;
}
// order-preserving float<->uint for atomicMax
__device__ __forceinline__ unsigned fenc(float f){
  unsigned u = __float_as_uint(f);
  return (u & 0x80000000u) ? ~u : (u | 0x80000000u);
}
__device__ __forceinline__ float fdec(unsigned e){
  unsigned u = (e & 0x80000000u) ? (e ^ 0x80000000u) : ~e;
  return __uint_as_float(u);
}

__device__ __forceinline__ void gload_lds16(const void* g, void* l){
  __builtin_amdgcn_global_load_lds(
      (const __attribute__((address_space(1))) unsigned*)g,
      (__attribute__((address_space(3))) unsigned*)l, 16, 0, 0);
}

// ================= mega-prep: weight packs + wvec + bias + degree count ====
// blocks 0..767: W1t row; 768..1023: W2t row; 1024: bias1; 1025: wvec;
// 1026..: edge degree count.
__global__ __launch_bounds__(256) void k_prep(
    const float* __restrict__ Wg, const float* __restrict__ Wa,
    const float* __restrict__ Wl, const float* __restrict__ Wr,
    const float* __restrict__ Wf,
    const float* __restrict__ att_src, const float* __restrict__ att_dst,
    const float* __restrict__ bg, const float* __restrict__ ba,
    const float* __restrict__ bs,
    const int* __restrict__ ecol,
    bf16* __restrict__ W1t, bf16* __restrict__ W2t,
    float* __restrict__ bias1, float* __restrict__ wsrc,
    float* __restrict__ wdst, int* __restrict__ cnt, int E)
{
  int b = blockIdx.x, t = threadIdx.x;
  if (b < 768){                       // W1t [768][256] blockdiag pack
    int n = b, k = t;
    float v = 0.f;
    if (n < 256)      { if (k < 128)  v = Wg[(size_t)k*D_H + n]; }
    else if (n < 512) { if (k >= 128) v = Wa[(size_t)(k-128)*D_H + (n-256)]; }
    else              { v = (k < 128) ? Wl[(size_t)k*D_H + (n-512)]
                                      : Wr[(size_t)(k-128)*D_H + (n-512)]; }
    W1t[(size_t)n*256 + k] = f2b(v);
  } else if (b < 1024){               // W2t [256][768] <- W_fus^T
    int n = b - 768;
    for (int k = t; k < D_CAT; k += 256)
      W2t[(size_t)n*D_CAT + k] = f2b(Wf[(size_t)k*D_H + n]);
  } else if (b == 1024){              // bias1 = [bg|ba|bs]
    bias1[t] = bg[t]; bias1[256+t] = ba[t]; bias1[512+t] = bs[t];
  } else if (b == 1025){              // wsrc/wdst = W_gat @ att_{src,dst}
    if (t < 128){
      float s1 = 0.f, s2 = 0.f;
      for (int j = 0; j < D_H; ++j){
        float w = Wa[(size_t)t*D_H + j];
        s1 = fmaf(w, att_src[j], s1);
        s2 = fmaf(w, att_dst[j], s2);
      }
      wsrc[t] = s1; wdst[t] = s2;
    }
  } else {                            // degree count
    int e = (b - 1026)*256 + t;
    if (e < E) atomicAdd(&cnt[ecol[e]], 1);
  }
}

// ================= fused cast + attention logits + max init =================
// one wave per node: xb = bf16(x); a_src/a_dst = x @ wsrc/wdst; maxenc init
__global__ __launch_bounds__(256) void k_asrc(const float* __restrict__ x,
                                              const float* __restrict__ wsrc,
                                              const float* __restrict__ wdst,
                                              bf16* __restrict__ xb,
                                              float* __restrict__ a_src,
                                              float* __restrict__ a_dst,
                                              unsigned* __restrict__ maxenc,
                                              int N){
  int w = threadIdx.x >> 6, l = threadIdx.x & 63;
  int c = blockIdx.x*4 + w;
  if (c >= N) return;
  float2 xv = *(const float2*)(x + (size_t)c*D_IN + 2*l);
  *(unsigned*)(xb + (size_t)c*D_IN + 2*l) = packb(xv.x, xv.y);
  float s1 = xv.x*wsrc[2*l] + xv.y*wsrc[2*l+1];
  float s2 = xv.x*wdst[2*l] + xv.y*wdst[2*l+1];
  #pragma unroll
  for (int o = 32; o > 0; o >>= 1){
    s1 += __shfl_down(s1, o);
    s2 += __shfl_down(s2, o);
  }
  if (l == 0){ a_src[c] = s1; a_dst[c] = s2; maxenc[c] = fenc(s1); }
}

// ================= CSR scans (dis fused into scanA) =================
__global__ __launch_bounds__(256) void k_scanA(const int* __restrict__ cnt,
                                               int* __restrict__ indptr,
                                               int* __restrict__ bsum,
                                               float* __restrict__ dis, int N){
  __shared__ int s[256];
  int t = threadIdx.x, i = blockIdx.x*256 + t;
  int v = (i < N) ? cnt[i] : 0;
  s[t] = v; __syncthreads();
  #pragma unroll
  for (int d = 1; d < 256; d <<= 1){
    int tmp = (t >= d) ? s[t-d] : 0;
    __syncthreads();
    s[t] += tmp;
    __syncthreads();
  }
  if (i < N){
    indptr[i] = s[t] - v;
    dis[i] = rsqrtf((float)v + 1.0f);
  }
  if (t == 255) bsum[blockIdx.x] = s[255];
}

__global__ __launch_bounds__(256) void k_scanB(const int* __restrict__ bsum,
                                               int* __restrict__ boff,
                                               int* __restrict__ indptr,
                                               int nb, int N, int E){
  __shared__ int s[256];
  int t = threadIdx.x;
  int v = (t < nb) ? bsum[t] : 0;
  s[t] = v; __syncthreads();
  #pragma unroll
  for (int d = 1; d < 256; d <<= 1){
    int tmp = (t >= d) ? s[t-d] : 0;
    __syncthreads();
    s[t] += tmp;
    __syncthreads();
  }
  boff[t] = s[t] - v;
  if (t == 0) indptr[N] = E;
}

__global__ __launch_bounds__(256) void k_scanC(int* __restrict__ indptr,
                                               const int* __restrict__ boff, int N){
  int i = blockIdx.x*256 + threadIdx.x;
  if (i < N) indptr[i] += boff[blockIdx.x];
}

// CSR fill + per-target a_src max (monotone lrelu => max moves inside)
__global__ __launch_bounds__(256) void k_fill(const int* __restrict__ row,
                                              const int* __restrict__ col,
                                              const int* __restrict__ indptr,
                                              int* __restrict__ cursor,
                                              int* __restrict__ esrc,
                                              const float* __restrict__ a_src,
                                              unsigned* __restrict__ maxenc,
                                              int E){
  int e = blockIdx.x*256 + threadIdx.x;
  if (e < E){
    int r = row[e], c = col[e];
    int p = indptr[c] + atomicAdd(&cursor[c], 1);
    esrc[p] = r;
    atomicMax(&maxenc[c], fenc(a_src[r]));
  }
}

// ================= x-space fused aggregation =================
// AGG row [512]: [0:128) gcn'  [128:256) gat'  [256:384) mean  [384:512) x
__global__ __launch_bounds__(256) void k_aggx(
    const int* __restrict__ indptr, const int* __restrict__ esrc,
    const bf16* __restrict__ xb,
    const float* __restrict__ a_src, const float* __restrict__ a_dst,
    const float* __restrict__ dis,
    const unsigned* __restrict__ maxenc,
    bf16* __restrict__ AGG, int N)
{
  int c = blockIdx.x;
  if (c >= N) return;
  int t = threadIdx.x;
  int beg = indptr[c], end = indptr[c+1];
  int deg = end - beg;
  float adst = a_dst[c], dc = dis[c];
  float eself = lrelu(a_src[c] + adst);
  float m = lrelu(fdec(maxenc[c]) + adst);   // includes self (init) + all edges

  __shared__ int   s_src[256];
  __shared__ float s_pe[256];
  __shared__ float s_ds[256];
  __shared__ float pg[4][128], pa[4][128], ps[4][128];
  __shared__ float red[4];

  float p0 = __expf(eself - m);
  float z_loc = (t == 0) ? p0 : 0.f;

  int d2 = t & 63;   // dims 2*d2, 2*d2+1
  int g  = t >> 6;   // edge group 0..3
  float g0=0.f,g1=0.f,a0=0.f,a1=0.f,sg0=0.f,sg1=0.f;

  for (int ch0 = beg; ch0 < end; ch0 += 256){
    int n = min(256, end - ch0);
    __syncthreads();
    if (t < n){
      int s = esrc[ch0 + t];
      float pe = __expf(lrelu(a_src[s] + adst) - m);
      s_src[t] = s; s_pe[t] = pe; s_ds[t] = dis[s];
      z_loc += pe;
    }
    __syncthreads();
    int i = g;
    // 8-deep unroll: 8 independent gathers in flight per wave-group
    for (; i + 28 < n; i += 32){
      unsigned u[8]; float pe[8], ds[8];
      #pragma unroll
      for (int q = 0; q < 8; ++q){
        int s = s_src[i + 4*q];
        u[q] = *(const unsigned*)(xb + (size_t)s*D_IN + 2*d2);
      }
      #pragma unroll
      for (int q = 0; q < 8; ++q){ pe[q] = s_pe[i+4*q]; ds[q] = s_ds[i+4*q]; }
      #pragma unroll
      for (int q = 0; q < 8; ++q){
        float x0 = __uint_as_float(u[q] << 16);
        float x1 = __uint_as_float(u[q] & 0xffff0000u);
        g0 = fmaf(ds[q], x0, g0); g1 = fmaf(ds[q], x1, g1);
        a0 = fmaf(pe[q], x0, a0); a1 = fmaf(pe[q], x1, a1);
        sg0 += x0; sg1 += x1;
      }
    }
    for (; i < n; i += 4){
      int s = s_src[i];
      float pe = s_pe[i], ds = s_ds[i];
      unsigned u = *(const unsigned*)(xb + (size_t)s*D_IN + 2*d2);
      float x0 = __uint_as_float(u << 16);
      float x1 = __uint_as_float(u & 0xffff0000u);
      g0 = fmaf(ds, x0, g0); g1 = fmaf(ds, x1, g1);
      a0 = fmaf(pe, x0, a0); a1 = fmaf(pe, x1, a1);
      sg0 += x0; sg1 += x1;
    }
  }

  // z reduction
  #pragma unroll
  for (int o = 32; o > 0; o >>= 1) z_loc += __shfl_down(z_loc, o);
  if ((t & 63) == 0) red[t >> 6] = z_loc;
  __syncthreads();
  float z = red[0] + red[1] + red[2] + red[3];

  // cross-group reduce via LDS
  pg[g][2*d2] = g0; pg[g][2*d2+1] = g1;
  pa[g][2*d2] = a0; pa[g][2*d2+1] = a1;
  ps[g][2*d2] = sg0; ps[g][2*d2+1] = sg1;
  __syncthreads();

  if (t < 64){
    int d0 = 2*t, d1 = 2*t + 1;
    float G0 = pg[0][d0]+pg[1][d0]+pg[2][d0]+pg[3][d0];
    float G1 = pg[0][d1]+pg[1][d1]+pg[2][d1]+pg[3][d1];
    float A0 = pa[0][d0]+pa[1][d0]+pa[2][d0]+pa[3][d0];
    float A1 = pa[0][d1]+pa[1][d1]+pa[2][d1]+pa[3][d1];
    float S0 = ps[0][d0]+ps[1][d0]+ps[2][d0]+ps[3][d0];
    float S1 = ps[0][d1]+ps[1][d1]+ps[2][d1]+ps[3][d1];
    unsigned xu = *(const unsigned*)(xb + (size_t)c*D_IN + d0);
    float xc0 = __uint_as_float(xu << 16);
    float xc1 = __uint_as_float(xu & 0xffff0000u);
    float invz = 1.f / (z + 1e-16f);
    float invc = 1.f / fmaxf((float)deg, 1.f);
    unsigned* rowp = (unsigned*)(AGG + (size_t)c*512);
    rowp[t]        = packb(dc*(G0 + dc*xc0), dc*(G1 + dc*xc1));
    rowp[64 + t]   = packb((A0 + p0*xc0)*invz, (A1 + p0*xc1)*invz);
    rowp[128 + t]  = packb(S0*invc, S1*invc);
    rowp[192 + t]  = xu;
  }
}

// ================= fused MLP: out = relu(AGG@W1 + b1) @ W_fus + b_fus ======
__global__ __launch_bounds__(512, 4) void k_mlp(
    const bf16* __restrict__ AGG,   // [M][512]
    const bf16* __restrict__ W1t,   // [768][256]
    const bf16* __restrict__ W2t,   // [256][768]
    const float* __restrict__ bias1,// [768]
    const float* __restrict__ bias2,// [256]
    float* __restrict__ out, int M)
{
  __shared__ short A_res[4*64*64];   // 32KB
  __shared__ short Hc[2*64*64];      // 16KB
  __shared__ short SW[256*64];       // 32KB
  int tid  = threadIdx.x;
  int bm   = blockIdx.x*64;
  int wave = tid >> 6, lane = tid & 63;
  int l15  = lane & 15, l4 = lane >> 4;
  int wr   = (wave >> 2)*32;
  int wcol = wave & 3;

  f32x4 oacc[2][4] = {};

  #pragma unroll
  for (int i = 0; i < 4; ++i){
    int slot = i*512 + tid;
    int rr = (slot >> 3) & 63, gp = slot & 7;
    int gk = gp ^ (rr & 7);
    int p  = slot >> 9;
    int row = bm + rr; if (row >= M) row = M - 1;
    gload_lds16(AGG + (size_t)row*512 + p*64 + gk*8, A_res + (size_t)slot*8);
  }

  #pragma unroll
  for (int j = 0; j < 6; ++j){
    if (j == 4){
      #pragma unroll
      for (int i = 0; i < 4; ++i){
        int slot = i*512 + tid;
        int rr = (slot >> 3) & 63, gp = slot & 7;
        int gk = gp ^ (rr & 7);
        int p  = slot >> 9;
        int row = bm + rr; if (row >= M) row = M - 1;
        gload_lds16(AGG + (size_t)row*512 + 256 + p*64 + gk*8, A_res + (size_t)slot*8);
      }
    }
    const int p0 = (j < 2) ? 0 : ((j < 4) ? 2 : 0);
    const int np = (j < 4) ? 2 : 4;
    f32x4 hacc[2][2] = {};
    for (int pp = 0; pp < np; ++pp){
      int p = p0 + pp;
      __syncthreads();
      #pragma unroll
      for (int i = 0; i < 2; ++i){
        int slot = i*512 + tid;
        int r = slot >> 3, gp = slot & 7;
        int gk = gp ^ (r & 7);
        gload_lds16(W1t + (size_t)(j*128 + r)*256 + p*64 + gk*8, SW + (size_t)slot*8);
      }
      __syncthreads();
      #pragma unroll
      for (int kk = 0; kk < 2; ++kk){
        bf16x8 af[2], bfv[2];
        #pragma unroll
        for (int mi = 0; mi < 2; ++mi){
          int r = wr + mi*16 + l15;
          int gk = kk*4 + l4;
          af[mi] = *(const bf16x8*)(A_res + p*4096 + r*64 + ((gk ^ (r & 7))*8));
        }
        #pragma unroll
        for (int ni = 0; ni < 2; ++ni){
          int r = wcol*32 + ni*16 + l15;
          int gk = kk*4 + l4;
          bfv[ni] = *(const bf16x8*)(SW + r*64 + ((gk ^ (r & 7))*8));
        }
        #pragma unroll
        for (int mi = 0; mi < 2; ++mi)
          #pragma unroll
          for (int ni = 0; ni < 2; ++ni)
            hacc[mi][ni] = __builtin_amdgcn_mfma_f32_16x16x32_bf16(
                               af[mi], bfv[ni], hacc[mi][ni], 0, 0, 0);
      }
    }
    #pragma unroll
    for (int mi = 0; mi < 2; ++mi)
      #pragma unroll
      for (int ni = 0; ni < 2; ++ni){
        int cc = wcol*32 + ni*16 + l15;
        float bb = bias1[j*128 + cc];
        int q = cc >> 6, g8 = (cc >> 3) & 7, e = cc & 7;
        #pragma unroll
        for (int r = 0; r < 4; ++r){
          int rr = wr + mi*16 + l4*4 + r;
          float v = fmaxf(hacc[mi][ni][r] + bb, 0.f);
          Hc[q*4096 + rr*64 + ((g8 ^ (rr & 7))*8) + e] = bbits(v);
        }
      }
    #pragma unroll
    for (int q = 0; q < 2; ++q){
      __syncthreads();
      #pragma unroll
      for (int i = 0; i < 4; ++i){
        int slot = i*512 + tid;
        int r = slot >> 3, gp = slot & 7;
        int gk = gp ^ (r & 7);
        gload_lds16(W2t + (size_t)r*768 + j*128 + q*64 + gk*8, SW + (size_t)slot*8);
      }
      __syncthreads();
      #pragma unroll
      for (int kk = 0; kk < 2; ++kk){
        bf16x8 af[2], bfv[4];
        #pragma unroll
        for (int mi = 0; mi < 2; ++mi){
          int r = wr + mi*16 + l15;
          int gk = kk*4 + l4;
          af[mi] = *(const bf16x8*)(Hc + q*4096 + r*64 + ((gk ^ (r & 7))*8));
        }
        #pragma unroll
        for (int ni = 0; ni < 4; ++ni){
          int r = wcol*64 + ni*16 + l15;
          int gk = kk*4 + l4;
          bfv[ni] = *(const bf16x8*)(SW + r*64 + ((gk ^ (r & 7))*8));
        }
        #pragma unroll
        for (int mi = 0; mi < 2; ++mi)
          #pragma unroll
          for (int ni = 0; ni < 4; ++ni)
            oacc[mi][ni] = __builtin_amdgcn_mfma_f32_16x16x32_bf16(
                               af[mi], bfv[ni], oacc[mi][ni], 0, 0, 0);
      }
    }
  }

  #pragma unroll
  for (int mi = 0; mi < 2; ++mi)
    #pragma unroll
    for (int r = 0; r < 4; ++r){
      int row = bm + wr + mi*16 + l4*4 + r;
      if (row >= M) continue;
      #pragma unroll
      for (int ni = 0; ni < 4; ++ni){
        int col = wcol*64 + ni*16 + l15;
        out[(size_t)row*256 + col] = oacc[mi][ni][r] + bias2[col];
      }
    }
}

// ================= host =================
static inline char* carve(char*& p, size_t bytes){
  char* r = p;
  p += (bytes + 255) & ~(size_t)255;
  return r;
}

extern "C" void kernel_launch(void* const* d_in, const int* in_sizes, int n_in,
                              void* d_out, int out_size, void* d_ws, size_t ws_size,
                              hipStream_t stream) {
  const float* x        = (const float*)d_in[0];
  const int*   ei       = (const int*)  d_in[1];
  const float* W_gcn    = (const float*)d_in[2];
  const float* b_gcn    = (const float*)d_in[3];
  const float* W_gat    = (const float*)d_in[4];
  const float* att_src  = (const float*)d_in[5];
  const float* att_dst  = (const float*)d_in[6];
  const float* b_gat    = (const float*)d_in[7];
  const float* W_sage_l = (const float*)d_in[8];
  const float* b_sage_l = (const float*)d_in[9];
  const float* W_sage_r = (const float*)d_in[10];
  const float* W_fus    = (const float*)d_in[11];
  const float* b_fus    = (const float*)d_in[12];

  const int N = in_sizes[0] / D_IN;
  const int E = in_sizes[1] / 2;
  const int* erow = ei;
  const int* ecol = ei + E;

  char* p = (char*)d_ws;
  bf16*     AGG    = (bf16*)    carve(p, (size_t)N*512*2);
  bf16*     xb     = (bf16*)    carve(p, (size_t)N*D_IN*2);
  bf16*     W1t    = (bf16*)    carve(p, (size_t)D_CAT*256*2);
  bf16*     W2t    = (bf16*)    carve(p, (size_t)256*D_CAT*2);
  float*    bias1  = (float*)   carve(p, D_CAT*4);
  float*    wsrc   = (float*)   carve(p, D_IN*4);
  float*    wdst   = (float*)   carve(p, D_IN*4);
  float*    a_src  = (float*)   carve(p, (size_t)N*4);
  float*    a_dst  = (float*)   carve(p, (size_t)N*4);
  float*    dis    = (float*)   carve(p, (size_t)N*4);
  unsigned* maxenc = (unsigned*)carve(p, (size_t)N*4);
  int*      cnt    = (int*)     carve(p, (size_t)N*4);
  int*      cursor = (int*)     carve(p, (size_t)N*4);
  int*      indptr = (int*)     carve(p, (size_t)(N+1)*4);
  int*      bsum   = (int*)     carve(p, 256*4);
  int*      boff   = (int*)     carve(p, 256*4);
  int*      esrc   = (int*)     carve(p, (size_t)E*4);
  (void)ws_size; (void)n_in; (void)out_size;

  hipMemsetAsync(cnt,    0, (size_t)N*4, stream);
  hipMemsetAsync(cursor, 0, (size_t)N*4, stream);

  const int nb = (N + 255) / 256;
  const int eb = (E + 255) / 256;

  // mega-prep: packs + wvec + bias + degree count
  k_prep<<<1026 + eb, 256, 0, stream>>>(W_gcn, W_gat, W_sage_l, W_sage_r, W_fus,
                                        att_src, att_dst, b_gcn, b_gat, b_sage_l,
                                        ecol, W1t, W2t, bias1, wsrc, wdst, cnt, E);

  // fused cast + logits + max-init (needs wvec from k_prep)
  k_asrc<<<(N + 3)/4, 256, 0, stream>>>(x, wsrc, wdst, xb, a_src, a_dst,
                                        maxenc, N);

  // CSR scans (dis fused) + fill (+ per-target a_src atomicMax)
  k_scanA<<<nb, 256, 0, stream>>>(cnt, indptr, bsum, dis, N);
  k_scanB<<<1, 256, 0, stream>>>(bsum, boff, indptr, nb, N, E);
  k_scanC<<<nb, 256, 0, stream>>>(indptr, boff, N);
  k_fill <<<eb, 256, 0, stream>>>(erow, ecol, indptr, cursor, esrc,
                                  a_src, maxenc, E);

  // x-space aggregation (max pass eliminated via monotone-lrelu + maxenc)
  k_aggx<<<N, 256, 0, stream>>>(indptr, esrc, xb, a_src, a_dst, dis,
                                maxenc, AGG, N);

  // fused 2-layer MLP: AGG -> out
  k_mlp<<<(N + 63)/64, 512, 0, stream>>>(AGG, W1t, W2t, bias1, b_fus,
                                         (float*)d_out, N);
}

// Round 13
// 338.161 us; speedup vs baseline: 1.1616x; 1.1616x over previous
//
#include <hip/hip_runtime.h>
#include <hip/hip_bf16.h>

typedef __hip_bfloat16 bf16;
typedef short bf16x8 __attribute__((ext_vector_type(8)));
typedef float f32x4  __attribute__((ext_vector_type(4)));

static constexpr int D_IN  = 128;
static constexpr int D_H   = 256;
static constexpr int D_CAT = 768;

__device__ __forceinline__ float lrelu(float v){ return v > 0.f ? v : 0.2f*v; }
__device__ __forceinline__ bf16  f2b(float v){ return __float2bfloat16(v); }
__device__ __forceinline__ unsigned packb(float lo, float hi){
  bf16 a = f2b(lo), b = f2b(hi);
  unsigned short ua, ub;
  __builtin_memcpy(&ua, &a, 2); __builtin_memcpy(&ub, &b, 2);
  return (unsigned)ua | ((unsigned)ub << 16);
}
__device__ __forceinline__ short bbits(float v){
  bf16 h = f2b(v); short s; __builtin_memcpy(&s, &h, 2); return s;
}
// order-preserving float<->uint for atomicMax
__device__ __forceinline__ unsigned fenc(float f){
  unsigned u = __float_as_uint(f);
  return (u & 0x80000000u) ? ~u : (u | 0x80000000u);
}
__device__ __forceinline__ float fdec(unsigned e){
  unsigned u = (e & 0x80000000u) ? (e ^ 0x80000000u) : ~e;
  return __uint_as_float(u);
}

__device__ __forceinline__ void gload_lds16(const void* g, void* l){
  __builtin_amdgcn_global_load_lds(
      (const __attribute__((address_space(1))) unsigned*)g,
      (__attribute__((address_space(3))) unsigned*)l, 16, 0, 0);
}

// ================= mega-prep: weight packs + wvec + bias + degree count ====
__global__ __launch_bounds__(256) void k_prep(
    const float* __restrict__ Wg, const float* __restrict__ Wa,
    const float* __restrict__ Wl, const float* __restrict__ Wr,
    const float* __restrict__ Wf,
    const float* __restrict__ att_src, const float* __restrict__ att_dst,
    const float* __restrict__ bg, const float* __restrict__ ba,
    const float* __restrict__ bs,
    const int* __restrict__ ecol,
    bf16* __restrict__ W1t, bf16* __restrict__ W2t,
    float* __restrict__ bias1, float* __restrict__ wsrc,
    float* __restrict__ wdst, int* __restrict__ cnt, int E)
{
  int b = blockIdx.x, t = threadIdx.x;
  if (b < 768){                       // W1t [768][256] blockdiag pack
    int n = b, k = t;
    float v = 0.f;
    if (n < 256)      { if (k < 128)  v = Wg[(size_t)k*D_H + n]; }
    else if (n < 512) { if (k >= 128) v = Wa[(size_t)(k-128)*D_H + (n-256)]; }
    else              { v = (k < 128) ? Wl[(size_t)k*D_H + (n-512)]
                                      : Wr[(size_t)(k-128)*D_H + (n-512)]; }
    W1t[(size_t)n*256 + k] = f2b(v);
  } else if (b < 1024){               // W2t [256][768] <- W_fus^T
    int n = b - 768;
    for (int k = t; k < D_CAT; k += 256)
      W2t[(size_t)n*D_CAT + k] = f2b(Wf[(size_t)k*D_H + n]);
  } else if (b == 1024){              // bias1 = [bg|ba|bs]
    bias1[t] = bg[t]; bias1[256+t] = ba[t]; bias1[512+t] = bs[t];
  } else if (b == 1025){              // wsrc/wdst = W_gat @ att_{src,dst}
    if (t < 128){
      float s1 = 0.f, s2 = 0.f;
      for (int j = 0; j < D_H; ++j){
        float w = Wa[(size_t)t*D_H + j];
        s1 = fmaf(w, att_src[j], s1);
        s2 = fmaf(w, att_dst[j], s2);
      }
      wsrc[t] = s1; wdst[t] = s2;
    }
  } else {                            // degree count
    int e = (b - 1026)*256 + t;
    if (e < E) atomicAdd(&cnt[ecol[e]], 1);
  }
}

// ================= fused cast + attention logits + max init =================
__global__ __launch_bounds__(256) void k_asrc(const float* __restrict__ x,
                                              const float* __restrict__ wsrc,
                                              const float* __restrict__ wdst,
                                              bf16* __restrict__ xb,
                                              float* __restrict__ a_src,
                                              float* __restrict__ a_dst,
                                              unsigned* __restrict__ maxenc,
                                              int N){
  int w = threadIdx.x >> 6, l = threadIdx.x & 63;
  int c = blockIdx.x*4 + w;
  if (c >= N) return;
  float2 xv = *(const float2*)(x + (size_t)c*D_IN + 2*l);
  *(unsigned*)(xb + (size_t)c*D_IN + 2*l) = packb(xv.x, xv.y);
  float s1 = xv.x*wsrc[2*l] + xv.y*wsrc[2*l+1];
  float s2 = xv.x*wdst[2*l] + xv.y*wdst[2*l+1];
  #pragma unroll
  for (int o = 32; o > 0; o >>= 1){
    s1 += __shfl_down(s1, o);
    s2 += __shfl_down(s2, o);
  }
  if (l == 0){ a_src[c] = s1; a_dst[c] = s2; maxenc[c] = fenc(s1); }
}

// ================= CSR scans (dis fused into scanA) =================
__global__ __launch_bounds__(256) void k_scanA(const int* __restrict__ cnt,
                                               int* __restrict__ indptr,
                                               int* __restrict__ bsum,
                                               float* __restrict__ dis, int N){
  __shared__ int s[256];
  int t = threadIdx.x, i = blockIdx.x*256 + t;
  int v = (i < N) ? cnt[i] : 0;
  s[t] = v; __syncthreads();
  #pragma unroll
  for (int d = 1; d < 256; d <<= 1){
    int tmp = (t >= d) ? s[t-d] : 0;
    __syncthreads();
    s[t] += tmp;
    __syncthreads();
  }
  if (i < N){
    indptr[i] = s[t] - v;
    dis[i] = rsqrtf((float)v + 1.0f);
  }
  if (t == 255) bsum[blockIdx.x] = s[255];
}

__global__ __launch_bounds__(256) void k_scanB(const int* __restrict__ bsum,
                                               int* __restrict__ boff,
                                               int* __restrict__ indptr,
                                               int nb, int N, int E){
  __shared__ int s[256];
  int t = threadIdx.x;
  int v = (t < nb) ? bsum[t] : 0;
  s[t] = v; __syncthreads();
  #pragma unroll
  for (int d = 1; d < 256; d <<= 1){
    int tmp = (t >= d) ? s[t-d] : 0;
    __syncthreads();
    s[t] += tmp;
    __syncthreads();
  }
  boff[t] = s[t] - v;
  if (t == 0) indptr[N] = E;
}

__global__ __launch_bounds__(256) void k_scanC(int* __restrict__ indptr,
                                               const int* __restrict__ boff, int N){
  int i = blockIdx.x*256 + threadIdx.x;
  if (i < N) indptr[i] += boff[blockIdx.x];
}

// CSR fill + per-target a_src max (monotone lrelu => max moves inside)
__global__ __launch_bounds__(256) void k_fill(const int* __restrict__ row,
                                              const int* __restrict__ col,
                                              const int* __restrict__ indptr,
                                              int* __restrict__ cursor,
                                              int* __restrict__ esrc,
                                              const float* __restrict__ a_src,
                                              unsigned* __restrict__ maxenc,
                                              int E){
  int e = blockIdx.x*256 + threadIdx.x;
  if (e < E){
    int r = row[e], c = col[e];
    int p = indptr[c] + atomicAdd(&cursor[c], 1);
    esrc[p] = r;
    atomicMax(&maxenc[c], fenc(a_src[r]));
  }
}

// ================= x-space fused aggregation: ONE WAVE PER NODE ============
// Lane l owns dims 2l,2l+1. Coefficients computed lane-parallel, broadcast
// via __shfl; 8 independent 256B gathers in flight per wave, incl. tail.
// No LDS, no barriers. AGG row [512]: gcn' | gat' | mean | x
__global__ __launch_bounds__(256) void k_aggx(
    const int* __restrict__ indptr, const int* __restrict__ esrc,
    const bf16* __restrict__ xb,
    const float* __restrict__ a_src, const float* __restrict__ a_dst,
    const float* __restrict__ dis,
    const unsigned* __restrict__ maxenc,
    bf16* __restrict__ AGG, int N)
{
  int w = threadIdx.x >> 6, l = threadIdx.x & 63;
  int c = blockIdx.x*4 + w;
  if (c >= N) return;
  int beg = indptr[c], end = indptr[c+1];
  int deg = end - beg;
  float adst = a_dst[c], dc = dis[c];
  float eself = lrelu(a_src[c] + adst);
  float m  = lrelu(fdec(maxenc[c]) + adst);   // analytic max (self + edges)
  float p0 = __expf(eself - m);

  float g0=0.f,g1=0.f,a0=0.f,a1=0.f,sg0=0.f,sg1=0.f;
  float z_lane = 0.f;

  for (int ch0 = beg; ch0 < end; ch0 += 64){
    int cn = min(64, end - ch0);
    // producer: lane l -> edge ch0+l coefficients (0 for invalid lanes)
    int  idx   = ch0 + ((l < cn) ? l : 0);
    int  src_l = esrc[idx];
    float pe_l = 0.f, ds_l = 0.f;
    if (l < cn){
      pe_l = __expf(lrelu(a_src[src_l] + adst) - m);
      ds_l = dis[src_l];
      z_lane += pe_l;
    }

    int e = 0;
    for (; e + 7 < cn; e += 8){
      int s[8]; unsigned u[8]; float pe[8], ds[8];
      #pragma unroll
      for (int q = 0; q < 8; ++q){
        s[q] = __shfl(src_l, e + q);
        u[q] = *(const unsigned*)(xb + (size_t)s[q]*D_IN + 2*l);
      }
      #pragma unroll
      for (int q = 0; q < 8; ++q){
        pe[q] = __shfl(pe_l, e + q);
        ds[q] = __shfl(ds_l, e + q);
      }
      #pragma unroll
      for (int q = 0; q < 8; ++q){
        float x0 = __uint_as_float(u[q] << 16);
        float x1 = __uint_as_float(u[q] & 0xffff0000u);
        g0 = fmaf(ds[q], x0, g0); g1 = fmaf(ds[q], x1, g1);
        a0 = fmaf(pe[q], x0, a0); a1 = fmaf(pe[q], x1, a1);
        sg0 += x0; sg1 += x1;
      }
    }
    if (e < cn){
      // masked batch: clamp lane index; pe/ds are 0 on invalid lanes
      int s[8]; unsigned u[8]; float pe[8], ds[8], mk[8];
      #pragma unroll
      for (int q = 0; q < 8; ++q){
        int ee = e + q; ee = (ee < cn) ? ee : (cn - 1);
        s[q] = __shfl(src_l, ee);
        u[q] = *(const unsigned*)(xb + (size_t)s[q]*D_IN + 2*l);
      }
      #pragma unroll
      for (int q = 0; q < 8; ++q){
        bool v = (e + q) < cn;
        int ee = v ? (e + q) : 63;       // lane 63 has pe=ds=0 when cn<64
        pe[q] = __shfl(pe_l, ee);
        ds[q] = __shfl(ds_l, ee);
        mk[q] = v ? 1.f : 0.f;
      }
      #pragma unroll
      for (int q = 0; q < 8; ++q){
        float x0 = __uint_as_float(u[q] << 16);
        float x1 = __uint_as_float(u[q] & 0xffff0000u);
        g0 = fmaf(ds[q], x0, g0); g1 = fmaf(ds[q], x1, g1);
        a0 = fmaf(pe[q], x0, a0); a1 = fmaf(pe[q], x1, a1);
        sg0 = fmaf(mk[q], x0, sg0); sg1 = fmaf(mk[q], x1, sg1);
      }
    }
  }

  // z: wave-reduce + broadcast
  float z = z_lane;
  #pragma unroll
  for (int o = 32; o > 0; o >>= 1) z += __shfl_down(z, o);
  z = __shfl(z, 0) + p0;

  unsigned xu = *(const unsigned*)(xb + (size_t)c*D_IN + 2*l);
  float xc0 = __uint_as_float(xu << 16);
  float xc1 = __uint_as_float(xu & 0xffff0000u);
  float invz = 1.f / (z + 1e-16f);
  float invc = 1.f / fmaxf((float)deg, 1.f);
  unsigned* rowp = (unsigned*)(AGG + (size_t)c*512);
  rowp[l]       = packb(dc*(g0 + dc*xc0), dc*(g1 + dc*xc1));
  rowp[64 + l]  = packb((a0 + p0*xc0)*invz, (a1 + p0*xc1)*invz);
  rowp[128 + l] = packb(sg0*invc, sg1*invc);
  rowp[192 + l] = xu;
}

// ================= fused MLP: out = relu(AGG@W1 + b1) @ W_fus + b_fus ======
__global__ __launch_bounds__(512, 4) void k_mlp(
    const bf16* __restrict__ AGG,   // [M][512]
    const bf16* __restrict__ W1t,   // [768][256]
    const bf16* __restrict__ W2t,   // [256][768]
    const float* __restrict__ bias1,// [768]
    const float* __restrict__ bias2,// [256]
    float* __restrict__ out, int M)
{
  __shared__ short A_res[4*64*64];   // 32KB
  __shared__ short Hc[2*64*64];      // 16KB
  __shared__ short SW[256*64];       // 32KB
  int tid  = threadIdx.x;
  int bm   = blockIdx.x*64;
  int wave = tid >> 6, lane = tid & 63;
  int l15  = lane & 15, l4 = lane >> 4;
  int wr   = (wave >> 2)*32;
  int wcol = wave & 3;

  f32x4 oacc[2][4] = {};

  #pragma unroll
  for (int i = 0; i < 4; ++i){
    int slot = i*512 + tid;
    int rr = (slot >> 3) & 63, gp = slot & 7;
    int gk = gp ^ (rr & 7);
    int p  = slot >> 9;
    int row = bm + rr; if (row >= M) row = M - 1;
    gload_lds16(AGG + (size_t)row*512 + p*64 + gk*8, A_res + (size_t)slot*8);
  }

  #pragma unroll
  for (int j = 0; j < 6; ++j){
    if (j == 4){
      #pragma unroll
      for (int i = 0; i < 4; ++i){
        int slot = i*512 + tid;
        int rr = (slot >> 3) & 63, gp = slot & 7;
        int gk = gp ^ (rr & 7);
        int p  = slot >> 9;
        int row = bm + rr; if (row >= M) row = M - 1;
        gload_lds16(AGG + (size_t)row*512 + 256 + p*64 + gk*8, A_res + (size_t)slot*8);
      }
    }
    const int p0 = (j < 2) ? 0 : ((j < 4) ? 2 : 0);
    const int np = (j < 4) ? 2 : 4;
    f32x4 hacc[2][2] = {};
    for (int pp = 0; pp < np; ++pp){
      int p = p0 + pp;
      __syncthreads();
      #pragma unroll
      for (int i = 0; i < 2; ++i){
        int slot = i*512 + tid;
        int r = slot >> 3, gp = slot & 7;
        int gk = gp ^ (r & 7);
        gload_lds16(W1t + (size_t)(j*128 + r)*256 + p*64 + gk*8, SW + (size_t)slot*8);
      }
      __syncthreads();
      #pragma unroll
      for (int kk = 0; kk < 2; ++kk){
        bf16x8 af[2], bfv[2];
        #pragma unroll
        for (int mi = 0; mi < 2; ++mi){
          int r = wr + mi*16 + l15;
          int gk = kk*4 + l4;
          af[mi] = *(const bf16x8*)(A_res + p*4096 + r*64 + ((gk ^ (r & 7))*8));
        }
        #pragma unroll
        for (int ni = 0; ni < 2; ++ni){
          int r = wcol*32 + ni*16 + l15;
          int gk = kk*4 + l4;
          bfv[ni] = *(const bf16x8*)(SW + r*64 + ((gk ^ (r & 7))*8));
        }
        #pragma unroll
        for (int mi = 0; mi < 2; ++mi)
          #pragma unroll
          for (int ni = 0; ni < 2; ++ni)
            hacc[mi][ni] = __builtin_amdgcn_mfma_f32_16x16x32_bf16(
                               af[mi], bfv[ni], hacc[mi][ni], 0, 0, 0);
      }
    }
    #pragma unroll
    for (int mi = 0; mi < 2; ++mi)
      #pragma unroll
      for (int ni = 0; ni < 2; ++ni){
        int cc = wcol*32 + ni*16 + l15;
        float bb = bias1[j*128 + cc];
        int q = cc >> 6, g8 = (cc >> 3) & 7, e = cc & 7;
        #pragma unroll
        for (int r = 0; r < 4; ++r){
          int rr = wr + mi*16 + l4*4 + r;
          float v = fmaxf(hacc[mi][ni][r] + bb, 0.f);
          Hc[q*4096 + rr*64 + ((g8 ^ (rr & 7))*8) + e] = bbits(v);
        }
      }
    #pragma unroll
    for (int q = 0; q < 2; ++q){
      __syncthreads();
      #pragma unroll
      for (int i = 0; i < 4; ++i){
        int slot = i*512 + tid;
        int r = slot >> 3, gp = slot & 7;
        int gk = gp ^ (r & 7);
        gload_lds16(W2t + (size_t)r*768 + j*128 + q*64 + gk*8, SW + (size_t)slot*8);
      }
      __syncthreads();
      #pragma unroll
      for (int kk = 0; kk < 2; ++kk){
        bf16x8 af[2], bfv[4];
        #pragma unroll
        for (int mi = 0; mi < 2; ++mi){
          int r = wr + mi*16 + l15;
          int gk = kk*4 + l4;
          af[mi] = *(const bf16x8*)(Hc + q*4096 + r*64 + ((gk ^ (r & 7))*8));
        }
        #pragma unroll
        for (int ni = 0; ni < 4; ++ni){
          int r = wcol*64 + ni*16 + l15;
          int gk = kk*4 + l4;
          bfv[ni] = *(const bf16x8*)(SW + r*64 + ((gk ^ (r & 7))*8));
        }
        #pragma unroll
        for (int mi = 0; mi < 2; ++mi)
          #pragma unroll
          for (int ni = 0; ni < 4; ++ni)
            oacc[mi][ni] = __builtin_amdgcn_mfma_f32_16x16x32_bf16(
                               af[mi], bfv[ni], oacc[mi][ni], 0, 0, 0);
      }
    }
  }

  #pragma unroll
  for (int mi = 0; mi < 2; ++mi)
    #pragma unroll
    for (int r = 0; r < 4; ++r){
      int row = bm + wr + mi*16 + l4*4 + r;
      if (row >= M) continue;
      #pragma unroll
      for (int ni = 0; ni < 4; ++ni){
        int col = wcol*64 + ni*16 + l15;
        out[(size_t)row*256 + col] = oacc[mi][ni][r] + bias2[col];
      }
    }
}

// ================= host =================
static inline char* carve(char*& p, size_t bytes){
  char* r = p;
  p += (bytes + 255) & ~(size_t)255;
  return r;
}

extern "C" void kernel_launch(void* const* d_in, const int* in_sizes, int n_in,
                              void* d_out, int out_size, void* d_ws, size_t ws_size,
                              hipStream_t stream) {
  const float* x        = (const float*)d_in[0];
  const int*   ei       = (const int*)  d_in[1];
  const float* W_gcn    = (const float*)d_in[2];
  const float* b_gcn    = (const float*)d_in[3];
  const float* W_gat    = (const float*)d_in[4];
  const float* att_src  = (const float*)d_in[5];
  const float* att_dst  = (const float*)d_in[6];
  const float* b_gat    = (const float*)d_in[7];
  const float* W_sage_l = (const float*)d_in[8];
  const float* b_sage_l = (const float*)d_in[9];
  const float* W_sage_r = (const float*)d_in[10];
  const float* W_fus    = (const float*)d_in[11];
  const float* b_fus    = (const float*)d_in[12];

  const int N = in_sizes[0] / D_IN;
  const int E = in_sizes[1] / 2;
  const int* erow = ei;
  const int* ecol = ei + E;

  char* p = (char*)d_ws;
  bf16*     AGG    = (bf16*)    carve(p, (size_t)N*512*2);
  bf16*     xb     = (bf16*)    carve(p, (size_t)N*D_IN*2);
  bf16*     W1t    = (bf16*)    carve(p, (size_t)D_CAT*256*2);
  bf16*     W2t    = (bf16*)    carve(p, (size_t)256*D_CAT*2);
  float*    bias1  = (float*)   carve(p, D_CAT*4);
  float*    wsrc   = (float*)   carve(p, D_IN*4);
  float*    wdst   = (float*)   carve(p, D_IN*4);
  float*    a_src  = (float*)   carve(p, (size_t)N*4);
  float*    a_dst  = (float*)   carve(p, (size_t)N*4);
  float*    dis    = (float*)   carve(p, (size_t)N*4);
  unsigned* maxenc = (unsigned*)carve(p, (size_t)N*4);
  int*      cnt    = (int*)     carve(p, (size_t)N*4);
  int*      cursor = (int*)     carve(p, (size_t)N*4);
  int*      indptr = (int*)     carve(p, (size_t)(N+1)*4);
  int*      bsum   = (int*)     carve(p, 256*4);
  int*      boff   = (int*)     carve(p, 256*4);
  int*      esrc   = (int*)     carve(p, (size_t)E*4);
  (void)ws_size; (void)n_in; (void)out_size;

  hipMemsetAsync(cnt,    0, (size_t)N*4, stream);
  hipMemsetAsync(cursor, 0, (size_t)N*4, stream);

  const int nb = (N + 255) / 256;
  const int eb = (E + 255) / 256;

  // mega-prep: packs + wvec + bias + degree count
  k_prep<<<1026 + eb, 256, 0, stream>>>(W_gcn, W_gat, W_sage_l, W_sage_r, W_fus,
                                        att_src, att_dst, b_gcn, b_gat, b_sage_l,
                                        ecol, W1t, W2t, bias1, wsrc, wdst, cnt, E);

  // fused cast + logits + max-init
  k_asrc<<<(N + 3)/4, 256, 0, stream>>>(x, wsrc, wdst, xb, a_src, a_dst,
                                        maxenc, N);

  // CSR scans (dis fused) + fill (+ per-target a_src atomicMax)
  k_scanA<<<nb, 256, 0, stream>>>(cnt, indptr, bsum, dis, N);
  k_scanB<<<1, 256, 0, stream>>>(bsum, boff, indptr, nb, N, E);
  k_scanC<<<nb, 256, 0, stream>>>(indptr, boff, N);
  k_fill <<<eb, 256, 0, stream>>>(erow, ecol, indptr, cursor, esrc,
                                  a_src, maxenc, E);

  // x-space aggregation: one wave per node, 8-deep gather ILP
  k_aggx<<<(N + 3)/4, 256, 0, stream>>>(indptr, esrc, xb, a_src, a_dst, dis,
                                        maxenc, AGG, N);

  // fused 2-layer MLP: AGG -> out
  k_mlp<<<(N + 63)/64, 512, 0, stream>>>(AGG, W1t, W2t, bias1, b_fus,
                                         (float*)d_out, N);
}